// Round 2
// baseline (1104.259 us; speedup 1.0000x reference)
//
#include <hip/hip_runtime.h>
#include <cstdint>

#define S_LEN 3600
#define DMODEL 1536
#define LCTX 512
#define NH 12
#define HDIM 128
#define FFND 8960
#define SPAD_SELF 3616

typedef short v8s __attribute__((ext_vector_type(8)));
typedef float v4f __attribute__((ext_vector_type(4)));
typedef unsigned short u16b;
typedef unsigned int u32b;

__device__ __forceinline__ u16b f2b(float f){
  union { float f; u32b i; } x; x.f = f;
  u32b r = x.i + 0x7fffu + ((x.i >> 16) & 1u);
  return (u16b)(r >> 16);
}

__device__ __forceinline__ int swz4(int row){ return (row ^ (row >> 2)) & 3; }

// ---------------- small elementwise kernels ----------------
__global__ void add_vec(const float* __restrict__ a, const float* __restrict__ b,
                        float* __restrict__ o, int n){
  int i = blockIdx.x * 256 + threadIdx.x;
  if (i < n) o[i] = a[i] + b[i];
}

__global__ void f2b_kernel(const float* __restrict__ in, u16b* __restrict__ out, int n){
  int i = blockIdx.x * 256 + threadIdx.x;
  if (i < n) out[i] = f2b(in[i]);
}

// ---------------- fused transpose-convert of all weights ----------------
struct WJob { const float* W; u16b* WT; int K; int N; int t0; };
struct WJobs { WJob j[10]; };

__global__ __launch_bounds__(256) void wconv(WJobs jobs){
  __shared__ float tile[32][33];
  int b = blockIdx.x;
  int ji = 0;
  #pragma unroll
  for (int i = 0; i < 10; ++i) if (b >= jobs.j[i].t0) ji = i;
  WJob jb = jobs.j[ji];
  int rel = b - jb.t0;
  int ntn = jb.N / 32;
  int k0 = (rel / ntn) * 32, n0 = (rel % ntn) * 32;
  int tx = threadIdx.x & 31, ty = threadIdx.x >> 5;
  #pragma unroll
  for (int r = ty; r < 32; r += 8) tile[r][tx] = jb.W[(size_t)(k0 + r) * jb.N + n0 + tx];
  __syncthreads();
  #pragma unroll
  for (int r = ty; r < 32; r += 8) jb.WT[(size_t)(n0 + r) * jb.K + k0 + tx] = f2b(tile[tx][r]);
}

// ---------------- per-head V transpose: V[S][12*128] -> Vt[12][128][Spad] ----------------
__global__ __launch_bounds__(256) void vtrans(const u16b* __restrict__ V,
                                              u16b* __restrict__ Vt,
                                              int S, int Spad){
  __shared__ u16b t[32][136];
  int h = blockIdx.y, kb = blockIdx.x * 32, tid = threadIdx.x;
  int row = tid >> 3, ch = tid & 7;
  int key = kb + row;
  if (key < S){
    float4 a = *(const float4*)(V + (size_t)key * DMODEL + h * HDIM + ch * 16);
    float4 b = *(const float4*)(V + (size_t)key * DMODEL + h * HDIM + ch * 16 + 8);
    *(float4*)&t[row][ch * 16] = a;
    *(float4*)&t[row][ch * 16 + 8] = b;
  } else {
    float4 z = {0.f, 0.f, 0.f, 0.f};
    *(float4*)&t[row][ch * 16] = z;
    *(float4*)&t[row][ch * 16 + 8] = z;
  }
  __syncthreads();
  int hd = tid >> 1, kc = (tid & 1) * 16;
  u16b* dst = Vt + ((size_t)h * HDIM + hd) * Spad + kb + kc;
  #pragma unroll
  for (int e = 0; e < 16; e += 2){
    u32b pk = ((u32b)t[kc + e][hd]) | (((u32b)t[kc + e + 1][hd]) << 16);
    *(u32b*)(dst + e) = pk;
  }
}

// ---------------- LayerNorm (mod or affine) -> bf16 ----------------
__global__ __launch_bounds__(256) void ln_mod(const float* __restrict__ X,
                                              const float* __restrict__ gamma,
                                              const float* __restrict__ beta,
                                              float gadd, u16b* __restrict__ out){
  int row = blockIdx.x;
  const float* xr = X + (size_t)row * DMODEL;
  int tid = threadIdx.x;
  float v[6]; float s1 = 0.f, s2 = 0.f;
  #pragma unroll
  for (int j = 0; j < 6; ++j){ v[j] = xr[tid + j * 256]; s1 += v[j]; s2 += v[j] * v[j]; }
  #pragma unroll
  for (int o = 1; o < 64; o <<= 1){ s1 += __shfl_xor(s1, o); s2 += __shfl_xor(s2, o); }
  __shared__ float red[8];
  int wid = tid >> 6, lane = tid & 63;
  if (!lane){ red[wid * 2] = s1; red[wid * 2 + 1] = s2; }
  __syncthreads();
  s1 = red[0] + red[2] + red[4] + red[6];
  s2 = red[1] + red[3] + red[5] + red[7];
  float mu = s1 / DMODEL;
  float var = s2 / DMODEL - mu * mu;
  float rstd = rsqrtf(var + 1e-6f);
  #pragma unroll
  for (int j = 0; j < 6; ++j){
    int c = tid + j * 256;
    float g = gamma[c] + gadd;
    float b = beta[c];
    out[(size_t)row * DMODEL + c] = f2b((v[j] - mu) * rstd * g + b);
  }
}

// ---------------- RMSNorm (+optional RoPE) fp32 -> bf16 ----------------
__global__ __launch_bounds__(256) void rms_rope(const float* __restrict__ X,
                                                const float* __restrict__ w,
                                                const float* __restrict__ cosT,
                                                const float* __restrict__ sinT,
                                                u16b* __restrict__ out){
  int row = blockIdx.x;
  const float* xr = X + (size_t)row * DMODEL;
  int tid = threadIdx.x;
  float2 v[3]; float ss = 0.f;
  #pragma unroll
  for (int j = 0; j < 3; ++j){
    v[j] = *(const float2*)(xr + 2 * (tid + j * 256));
    ss += v[j].x * v[j].x + v[j].y * v[j].y;
  }
  #pragma unroll
  for (int o = 1; o < 64; o <<= 1) ss += __shfl_xor(ss, o);
  __shared__ float red[4];
  int wid = tid >> 6, lane = tid & 63;
  if (!lane) red[wid] = ss;
  __syncthreads();
  ss = red[0] + red[1] + red[2] + red[3];
  float rstd = rsqrtf(ss / DMODEL + 1e-6f);
  #pragma unroll
  for (int j = 0; j < 3; ++j){
    int p = tid + j * 256;
    float xe = v[j].x * rstd * w[2 * p];
    float xo = v[j].y * rstd * w[2 * p + 1];
    float oe, oo;
    if (cosT){
      int d = p & 63;
      float c = cosT[row * 64 + d], sn = sinT[row * 64 + d];
      oe = xe * c - xo * sn; oo = xe * sn + xo * c;
    } else { oe = xe; oo = xo; }
    u32b packed = ((u32b)f2b(oe)) | (((u32b)f2b(oo)) << 16);
    *(u32b*)(out + (size_t)row * DMODEL + 2 * p) = packed;
  }
}

// ---------------- bf16 MFMA GEMM: C = A[MxK] @ BT[NxK]^T + bias ----------------
// EPI: 0 = bf16 store, 1 = f32 store, 2 = f32 res + gate*(acc+bias), 3 = gelu->bf16
template<int EPI>
__global__ __launch_bounds__(256, 2) void gemm_bt(
    const u16b* __restrict__ A, const u16b* __restrict__ BT,
    const float* __restrict__ bias, const float* __restrict__ res,
    const float* __restrict__ gate, float* __restrict__ outF,
    u16b* __restrict__ outB, int M, int N, int K)
{
  __shared__ u16b Al[128 * 32];
  __shared__ u16b Bl[128 * 32];
  const int tid = threadIdx.x, lane = tid & 63, wid = tid >> 6;
  const int bm = blockIdx.x * 128, bn = blockIdx.y * 128;
  const int wm = (wid >> 1) * 64, wn = (wid & 1) * 64;
  v4f acc[4][4] = {};
  const int g0 = tid, g1 = tid + 256;
  const int r0 = g0 >> 2, c0 = g0 & 3, r1 = g1 >> 2, c1 = g1 & 3;
  const size_t a_off0 = (size_t)min(bm + r0, M - 1) * K + c0 * 8;
  const size_t a_off1 = (size_t)min(bm + r1, M - 1) * K + c1 * 8;
  const size_t b_off0 = (size_t)(bn + r0) * K + c0 * 8;
  const size_t b_off1 = (size_t)(bn + r1) * K + c1 * 8;
  char* Ab = (char*)Al; char* Bb = (char*)Bl;
  const int wA0 = r0 * 64 + ((c0 ^ swz4(r0)) * 16);
  const int wA1 = r1 * 64 + ((c1 ^ swz4(r1)) * 16);
  float4 ra0, ra1, rb0, rb1;
  auto ldg = [&](int k0){
    ra0 = *(const float4*)(A + a_off0 + k0);
    ra1 = *(const float4*)(A + a_off1 + k0);
    rb0 = *(const float4*)(BT + b_off0 + k0);
    rb1 = *(const float4*)(BT + b_off1 + k0);
  };
  auto stw = [&](){
    *(float4*)(Ab + wA0) = ra0; *(float4*)(Ab + wA1) = ra1;
    *(float4*)(Bb + wA0) = rb0; *(float4*)(Bb + wA1) = rb1;
  };
  const int nt = K / 32;
  ldg(0); stw(); __syncthreads();
  const int chk = lane >> 4, qr = lane & 15;
  for (int t = 0; t < nt; ++t){
    if (t + 1 < nt) ldg((t + 1) * 32);
    v8s af[4], bfr[4];
    #pragma unroll
    for (int f = 0; f < 4; ++f){
      int rowa = wm + f * 16 + qr;
      af[f] = *(const v8s*)(Ab + rowa * 64 + ((chk ^ swz4(rowa)) * 16));
      int rowb = wn + f * 16 + qr;
      bfr[f] = *(const v8s*)(Bb + rowb * 64 + ((chk ^ swz4(rowb)) * 16));
    }
    #pragma unroll
    for (int i = 0; i < 4; ++i)
      #pragma unroll
      for (int j = 0; j < 4; ++j)
        acc[i][j] = __builtin_amdgcn_mfma_f32_16x16x32_bf16(af[i], bfr[j], acc[i][j], 0, 0, 0);
    __syncthreads();
    if (t + 1 < nt){ stw(); __syncthreads(); }
  }
  const int rr = lane >> 4;
  #pragma unroll
  for (int i = 0; i < 4; ++i){
    #pragma unroll
    for (int j = 0; j < 4; ++j){
      int n = bn + wn + j * 16 + qr;
      float bv = bias ? bias[n] : 0.f;
      float gv = (EPI == 2 && gate) ? gate[n] : 1.f;
      #pragma unroll
      for (int r = 0; r < 4; ++r){
        int m = bm + wm + i * 16 + rr * 4 + r;
        if (m < M){
          float val = acc[i][j][r] + bv;
          size_t idx = (size_t)m * N + n;
          if (EPI == 0) outB[idx] = f2b(val);
          else if (EPI == 1) outF[idx] = val;
          else if (EPI == 2) outF[idx] = res[idx] + gv * val;
          else {
            float t3 = val * val * val;
            float th = tanhf(0.7978845608028654f * (val + 0.044715f * t3));
            outB[idx] = f2b(0.5f * val * (1.f + th));
          }
        }
      }
    }
  }
}

// ---------------- flash attention (1 head x 64 q-rows per block) ----------------
// V is pre-transposed per head: Vt[h][hd 0..127][Spad keys]
__global__ __launch_bounds__(256, 2) void flash_attn(
    const u16b* __restrict__ Q, const u16b* __restrict__ Kp,
    const u16b* __restrict__ Vt, u16b* __restrict__ O,
    int Sq, int Sk, int Spad)
{
  __shared__ u16b Klds[32 * 128];   // [key][hd], swizzled granules
  __shared__ u16b Vlds[128 * 32];   // [hd][key], swizzled granules
  __shared__ u16b Plds[4 * 16 * 32];
  const int tid = threadIdx.x, lane = tid & 63, wid = tid >> 6;
  const int h = blockIdx.y;
  const int q0 = blockIdx.x * 64 + wid * 16;
  const int qq = lane & 15, cc = lane >> 4;
  char* Kb = (char*)Klds; char* Vb = (char*)Vlds; char* Pb = (char*)Plds;

  v8s qf[4];
  {
    int qrow = min(q0 + qq, Sq - 1);
    const u16b* qp = Q + (size_t)qrow * DMODEL + h * HDIM + cc * 8;
    #pragma unroll
    for (int ks = 0; ks < 4; ++ks) qf[ks] = *(const v8s*)(qp + ks * 32);
  }
  float mrun = -1e30f, lrun = 0.f;
  v4f oacc[8] = {};
  const float scale = 0.08838834764831845f; // 1/sqrt(128)

  for (int kb0 = 0; kb0 < Sk; kb0 += 32){
    __syncthreads();
    #pragma unroll
    for (int c = 0; c < 2; ++c){
      int g = tid + c * 256;
      int krow = g >> 4, kgc = g & 15;
      int key = min(kb0 + krow, Sk - 1);
      *(float4*)(Kb + krow * 256 + ((kgc ^ (krow & 7)) * 16)) =
          *(const float4*)(Kp + (size_t)key * DMODEL + h * HDIM + kgc * 8);
      int vr = g >> 2, vc = g & 3;
      *(float4*)(Vb + vr * 64 + ((vc ^ swz4(vr)) * 16)) =
          *(const float4*)(Vt + ((size_t)h * HDIM + vr) * Spad + kb0 + vc * 8);
    }
    __syncthreads();

    float s[8];
    #pragma unroll
    for (int sub = 0; sub < 2; ++sub){
      v4f sa = {0.f, 0.f, 0.f, 0.f};
      #pragma unroll
      for (int ks = 0; ks < 4; ++ks){
        int row = sub * 16 + qq;
        v8s kf = *(const v8s*)(Kb + row * 256 + (((ks * 4 + cc) ^ (row & 7)) * 16));
        sa = __builtin_amdgcn_mfma_f32_16x16x32_bf16(kf, qf[ks], sa, 0, 0, 0);
      }
      #pragma unroll
      for (int r = 0; r < 4; ++r) s[sub * 4 + r] = sa[r] * scale;
    }
    if (kb0 + 32 > Sk){
      #pragma unroll
      for (int i = 0; i < 8; ++i){
        int key = kb0 + (i >> 2) * 16 + cc * 4 + (i & 3);
        if (key >= Sk) s[i] = -1e30f;
      }
    }
    float cmax = s[0];
    #pragma unroll
    for (int i = 1; i < 8; ++i) cmax = fmaxf(cmax, s[i]);
    cmax = fmaxf(cmax, __shfl_xor(cmax, 16));
    cmax = fmaxf(cmax, __shfl_xor(cmax, 32));
    float mnew = fmaxf(mrun, cmax);
    float alpha = __expf(mrun - mnew);
    mrun = mnew;
    float p[8]; float csum = 0.f;
    #pragma unroll
    for (int i = 0; i < 8; ++i){ p[i] = __expf(s[i] - mnew); csum += p[i]; }
    csum += __shfl_xor(csum, 16);
    csum += __shfl_xor(csum, 32);
    lrun = lrun * alpha + csum;

    #pragma unroll
    for (int sub = 0; sub < 2; ++sub){
      int key0 = sub * 16 + cc * 4;
      u32b u01 = ((u32b)f2b(p[sub * 4 + 0])) | (((u32b)f2b(p[sub * 4 + 1])) << 16);
      u32b u23 = ((u32b)f2b(p[sub * 4 + 2])) | (((u32b)f2b(p[sub * 4 + 3])) << 16);
      char* base = Pb + wid * 1024 + qq * 64 + (((key0 >> 3) ^ ((qq >> 1) & 3)) * 16) + (key0 & 7) * 2;
      *(u32b*)base = u01;
      *(u32b*)(base + 4) = u23;
    }
    float alr[4];
    #pragma unroll
    for (int r = 0; r < 4; ++r) alr[r] = __shfl(alpha, cc * 4 + r);
    #pragma unroll
    for (int f = 0; f < 8; ++f)
      #pragma unroll
      for (int r = 0; r < 4; ++r) oacc[f][r] *= alr[r];

    v8s pf = *(const v8s*)(Pb + wid * 1024 + qq * 64 + ((cc ^ ((qq >> 1) & 3)) * 16));

    #pragma unroll
    for (int hdb = 0; hdb < 8; ++hdb){
      int row = hdb * 16 + qq;
      v8s vf = *(const v8s*)(Vb + row * 64 + ((cc ^ swz4(row)) * 16));
      oacc[hdb] = __builtin_amdgcn_mfma_f32_16x16x32_bf16(pf, vf, oacc[hdb], 0, 0, 0);
    }
  }

  float linv = 1.f / lrun;
  float lr[4];
  #pragma unroll
  for (int r = 0; r < 4; ++r) lr[r] = __shfl(linv, cc * 4 + r);
  #pragma unroll
  for (int hdb = 0; hdb < 8; ++hdb)
    #pragma unroll
    for (int r = 0; r < 4; ++r){
      int qrow = q0 + cc * 4 + r;
      if (qrow < Sq)
        O[(size_t)qrow * DMODEL + h * HDIM + hdb * 16 + qq] = f2b(oacc[hdb][r] * lr[r]);
    }
}

// ---------------- host launch ----------------
extern "C" void kernel_launch(void* const* d_in, const int* in_sizes, int n_in,
                              void* d_out, int out_size, void* d_ws, size_t ws_size,
                              hipStream_t stream){
  (void)in_sizes; (void)n_in; (void)out_size; (void)ws_size;
  const float* x     = (const float*)d_in[0];
  const float* ctx   = (const float*)d_in[1];
  const float* t_mod = (const float*)d_in[2];
  const float* ropec = (const float*)d_in[3];
  const float* ropes = (const float*)d_in[4];
  const float* modu  = (const float*)d_in[5];
  const float* sa_qw = (const float*)d_in[6];  const float* sa_qb = (const float*)d_in[7];
  const float* sa_kw = (const float*)d_in[8];  const float* sa_kb = (const float*)d_in[9];
  const float* sa_vw = (const float*)d_in[10]; const float* sa_vb = (const float*)d_in[11];
  const float* sa_ow = (const float*)d_in[12]; const float* sa_ob = (const float*)d_in[13];
  const float* sa_nq = (const float*)d_in[14]; const float* sa_nk = (const float*)d_in[15];
  const float* ca_qw = (const float*)d_in[16]; const float* ca_qb = (const float*)d_in[17];
  const float* ca_kw = (const float*)d_in[18]; const float* ca_kb = (const float*)d_in[19];
  const float* ca_vw = (const float*)d_in[20]; const float* ca_vb = (const float*)d_in[21];
  const float* ca_ow = (const float*)d_in[22]; const float* ca_ob = (const float*)d_in[23];
  const float* ca_nq = (const float*)d_in[24]; const float* ca_nk = (const float*)d_in[25];
  const float* n3w   = (const float*)d_in[26]; const float* n3b   = (const float*)d_in[27];
  const float* fw1   = (const float*)d_in[28]; const float* fb1   = (const float*)d_in[29];
  const float* fw2   = (const float*)d_in[30]; const float* fb2   = (const float*)d_in[31];
  float* out = (float*)d_out;

  char* wsp = (char*)d_ws;
  size_t off = 0;
  auto alloc = [&](size_t b){ void* p = wsp + off; off += (b + 255) & ~(size_t)255; return p; };
  const size_t WW = (size_t)DMODEL * DMODEL * 2;
  // persistent (alive through FFN):
  float* modc = (float*)alloc(6 * DMODEL * 4);
  u16b* w1T   = (u16b*)alloc((size_t)FFND * DMODEL * 2);
  u16b* w2T   = (u16b*)alloc((size_t)DMODEL * FFND * 2);
  u16b* h_bf  = (u16b*)alloc((size_t)S_LEN * DMODEL * 2);
  float* pre0 = (float*)alloc((size_t)S_LEN * DMODEL * 4);
  // phase region (dead by FFN time) — fmid overlays it:
  size_t region0 = off;
  u16b* sa_qwT = (u16b*)alloc(WW);
  u16b* sa_kwT = (u16b*)alloc(WW);
  u16b* sa_vwT = (u16b*)alloc(WW);
  u16b* sa_owT = (u16b*)alloc(WW);
  u16b* ca_qwT = (u16b*)alloc(WW);
  u16b* ca_kwT = (u16b*)alloc(WW);
  u16b* ca_vwT = (u16b*)alloc(WW);
  u16b* ca_owT = (u16b*)alloc(WW);
  float* x2    = (float*)alloc((size_t)S_LEN * DMODEL * 4);
  float* pre2  = (float*)alloc((size_t)LCTX * DMODEL * 4);
  u16b* qb     = (u16b*)alloc((size_t)S_LEN * DMODEL * 2);
  u16b* kb     = (u16b*)alloc((size_t)S_LEN * DMODEL * 2);
  u16b* vb     = (u16b*)alloc((size_t)S_LEN * DMODEL * 2);
  u16b* ab     = (u16b*)alloc((size_t)S_LEN * DMODEL * 2);
  u16b* ctxb   = (u16b*)alloc((size_t)LCTX * DMODEL * 2);
  u16b* k2b    = (u16b*)alloc((size_t)LCTX * DMODEL * 2);
  u16b* v2b    = (u16b*)alloc((size_t)LCTX * DMODEL * 2);
  u16b* vts    = (u16b*)alloc((size_t)NH * HDIM * SPAD_SELF * 2);
  u16b* vtc    = (u16b*)alloc((size_t)NH * HDIM * LCTX * 2);
  // FFN-phase overlay (region contents are dead when fmid is written):
  u16b* fmid = (u16b*)(wsp + region0);

  add_vec<<<36, 256, 0, stream>>>(modu, t_mod, modc, 6 * DMODEL);

  WJobs jobs; int t = 0;
  auto addjob = [&](int i, const float* w_, u16b* wt, int K, int N){
    jobs.j[i].W = w_; jobs.j[i].WT = wt; jobs.j[i].K = K; jobs.j[i].N = N; jobs.j[i].t0 = t;
    t += (K / 32) * (N / 32);
  };
  addjob(0, sa_qw, sa_qwT, DMODEL, DMODEL);
  addjob(1, sa_kw, sa_kwT, DMODEL, DMODEL);
  addjob(2, sa_vw, sa_vwT, DMODEL, DMODEL);
  addjob(3, sa_ow, sa_owT, DMODEL, DMODEL);
  addjob(4, ca_qw, ca_qwT, DMODEL, DMODEL);
  addjob(5, ca_kw, ca_kwT, DMODEL, DMODEL);
  addjob(6, ca_vw, ca_vwT, DMODEL, DMODEL);
  addjob(7, ca_ow, ca_owT, DMODEL, DMODEL);
  addjob(8, fw1, w1T, DMODEL, FFND);
  addjob(9, fw2, w2T, FFND, DMODEL);
  wconv<<<t, 256, 0, stream>>>(jobs);

  f2b_kernel<<<(LCTX * DMODEL) / 256, 256, 0, stream>>>(ctx, ctxb, LCTX * DMODEL);

  // ---- self attention branch ----
  ln_mod<<<S_LEN, 256, 0, stream>>>(x, modc + DMODEL, modc, 1.f, h_bf);
  dim3 g12(29, 12), g42(4, 12);
  gemm_bt<1><<<g12, 256, 0, stream>>>(h_bf, sa_qwT, sa_qb, nullptr, nullptr, pre0, nullptr, S_LEN, DMODEL, DMODEL);
  gemm_bt<1><<<g12, 256, 0, stream>>>(h_bf, sa_kwT, sa_kb, nullptr, nullptr, x2, nullptr, S_LEN, DMODEL, DMODEL);
  gemm_bt<0><<<g12, 256, 0, stream>>>(h_bf, sa_vwT, sa_vb, nullptr, nullptr, nullptr, vb, S_LEN, DMODEL, DMODEL);
  rms_rope<<<S_LEN, 256, 0, stream>>>(pre0, sa_nq, ropec, ropes, qb);
  rms_rope<<<S_LEN, 256, 0, stream>>>(x2, sa_nk, ropec, ropes, kb);
  vtrans<<<dim3(113, 12), 256, 0, stream>>>(vb, vts, S_LEN, SPAD_SELF);
  flash_attn<<<dim3(57, 12), 256, 0, stream>>>(qb, kb, vts, ab, S_LEN, S_LEN, SPAD_SELF);
  gemm_bt<2><<<g12, 256, 0, stream>>>(ab, sa_owT, sa_ob, x, modc + 2 * DMODEL, x2, nullptr, S_LEN, DMODEL, DMODEL);

  // ---- cross attention branch ----
  ln_mod<<<S_LEN, 256, 0, stream>>>(x2, n3w, n3b, 0.f, h_bf);
  gemm_bt<1><<<g12, 256, 0, stream>>>(h_bf, ca_qwT, ca_qb, nullptr, nullptr, pre0, nullptr, S_LEN, DMODEL, DMODEL);
  gemm_bt<1><<<g42, 256, 0, stream>>>(ctxb, ca_kwT, ca_kb, nullptr, nullptr, pre2, nullptr, LCTX, DMODEL, DMODEL);
  gemm_bt<0><<<g42, 256, 0, stream>>>(ctxb, ca_vwT, ca_vb, nullptr, nullptr, nullptr, v2b, LCTX, DMODEL, DMODEL);
  rms_rope<<<S_LEN, 256, 0, stream>>>(pre0, ca_nq, nullptr, nullptr, qb);
  rms_rope<<<LCTX, 256, 0, stream>>>(pre2, ca_nk, nullptr, nullptr, k2b);
  vtrans<<<dim3(16, 12), 256, 0, stream>>>(v2b, vtc, LCTX, LCTX);
  flash_attn<<<dim3(57, 12), 256, 0, stream>>>(qb, k2b, vtc, ab, S_LEN, LCTX, LCTX);
  gemm_bt<2><<<g12, 256, 0, stream>>>(ab, ca_owT, ca_ob, x2, nullptr, pre0, nullptr, S_LEN, DMODEL, DMODEL);

  // ---- FFN ----
  ln_mod<<<S_LEN, 256, 0, stream>>>(pre0, modc + 4 * DMODEL, modc + 3 * DMODEL, 1.f, h_bf);
  gemm_bt<3><<<dim3(29, 70), 256, 0, stream>>>(h_bf, w1T, fb1, nullptr, nullptr, nullptr, fmid, S_LEN, FFND, DMODEL);
  gemm_bt<2><<<g12, 256, 0, stream>>>(fmid, w2T, fb2, pre0, modc + 5 * DMODEL, out, nullptr, S_LEN, DMODEL, FFND);
}